// Round 1
// baseline (7499.561 us; speedup 1.0000x reference)
//
#include <hip/hip_runtime.h>
#include <cstdint>
#include <cstddef>

// ---------------------------------------------------------------------------
// QwenDoubleStreamAttention — fp32 baseline.
//   B=2, S_img=2048, S_txt=256 (S=2304), D=3072, H=24, DH=128.
// Pipeline:
//   1) gemm_kernel<QKV=true>  : x@W+b for q,k,v (img and txt), scatter to
//      [B][H][S][DH] fp32 buffers in d_ws.
//   2) rmsrope_kernel         : per-head RMSNorm (q,k) + RoPE, in place.
//   3) attn_kernel            : flash-style online-softmax attention,
//      64x64 tiles, fp32, writes o as [B][S][H*DH].
//   4) gemm_kernel<QKV=false> : o@wo+bo -> d_out (img rows then txt rows).
// Workspace: 4 buffers x 14,155,776 fp32 = 226.5 MB.
// ---------------------------------------------------------------------------

#define D_MODEL 3072
#define NHEADS 24
#define DHEAD 128
#define S_IMGC 2048
#define S_TXTC 256
#define S_TOT 2304
#define BATCH 2
#define ATT_SCALE 0.08838834764831845f  // 128^-0.5

// ---------------------------------------------------------------------------
// GEMM: C = A @ W + bias.  A row m -> (b = m/rows_per_b, s = m%rows_per_b),
// A_row = A + b*A_bstride + (s+As_off)*D_MODEL.  BM=BN=128, BK=16,
// 256 threads, 8x8 micro-tile.  gridDim.z selects one of up to 3 (W,bias,C)
// sets (fused q/k/v).  QKV_STORE scatters into [B][H][S][DH] (h = blockIdx.y
// since BN == DHEAD); otherwise row-major C[m][n].
// ---------------------------------------------------------------------------
template <bool QKV_STORE>
__global__ __launch_bounds__(256) void gemm_kernel(
    const float* __restrict__ A, size_t A_bstride, int As_off, int rows_per_b,
    const float* __restrict__ W0, const float* __restrict__ W1, const float* __restrict__ W2,
    const float* __restrict__ b0p, const float* __restrict__ b1p, const float* __restrict__ b2p,
    float* __restrict__ C0, float* __restrict__ C1, float* __restrict__ C2,
    int C_s_off)
{
    constexpr int BM = 128, BN = 128, BK = 16;
    __shared__ float As[BK][BM + 4];
    __shared__ float Bs[BK][BN + 4];

    const int z = blockIdx.z;
    const float* __restrict__ W    = (z == 0) ? W0 : (z == 1) ? W1 : W2;
    const float* __restrict__ bias = (z == 0) ? b0p : (z == 1) ? b1p : b2p;
    float* __restrict__ C          = (z == 0) ? C0 : (z == 1) ? C1 : C2;

    const int tid = threadIdx.x;
    const int tx = tid & 15, ty = tid >> 4;
    const int m0 = blockIdx.x * BM;
    const int n0 = blockIdx.y * BN;

    float acc[8][8];
#pragma unroll
    for (int i = 0; i < 8; i++)
#pragma unroll
        for (int j = 0; j < 8; j++) acc[i][j] = 0.f;

    // A staging addresses: thread loads row ar, k-cols [ac4*4, ac4*4+8)
    const int ar = tid >> 1;            // 0..127
    const int ac4 = (tid & 1) * 2;      // 0 or 2 -> k offset 0 or 8
    const int am = m0 + ar;
    const float* __restrict__ arow =
        A + (size_t)(am / rows_per_b) * A_bstride +
        (size_t)(am % rows_per_b + As_off) * D_MODEL;

    for (int k0 = 0; k0 < D_MODEL; k0 += BK) {
        // global loads (regs)
        const float4 a0 = *(const float4*)(arow + k0 + ac4 * 4);
        const float4 a1 = *(const float4*)(arow + k0 + ac4 * 4 + 4);
        const int f0 = tid, f1 = tid + 256;
        const float4 bv0 = *(const float4*)(W + (size_t)(k0 + (f0 >> 5)) * D_MODEL + n0 + (f0 & 31) * 4);
        const float4 bv1 = *(const float4*)(W + (size_t)(k0 + (f1 >> 5)) * D_MODEL + n0 + (f1 & 31) * 4);

        __syncthreads();  // previous tile's compute done
        As[ac4 * 4 + 0][ar] = a0.x;
        As[ac4 * 4 + 1][ar] = a0.y;
        As[ac4 * 4 + 2][ar] = a0.z;
        As[ac4 * 4 + 3][ar] = a0.w;
        As[ac4 * 4 + 4][ar] = a1.x;
        As[ac4 * 4 + 5][ar] = a1.y;
        As[ac4 * 4 + 6][ar] = a1.z;
        As[ac4 * 4 + 7][ar] = a1.w;
        *(float4*)&Bs[f0 >> 5][(f0 & 31) * 4] = bv0;
        *(float4*)&Bs[f1 >> 5][(f1 & 31) * 4] = bv1;
        __syncthreads();

#pragma unroll
        for (int k = 0; k < BK; k++) {
            alignas(16) float a[8], b[8];
            *(float4*)&a[0] = *(float4*)&As[k][ty * 8];
            *(float4*)&a[4] = *(float4*)&As[k][ty * 8 + 4];
            // split-column B fragment: cols tx*4.. and 64+tx*4.. (bank-friendly)
            *(float4*)&b[0] = *(float4*)&Bs[k][tx * 4];
            *(float4*)&b[4] = *(float4*)&Bs[k][64 + tx * 4];
#pragma unroll
            for (int i = 0; i < 8; i++)
#pragma unroll
                for (int j = 0; j < 8; j++) acc[i][j] = fmaf(a[i], b[j], acc[i][j]);
        }
    }

    // epilogue
#pragma unroll
    for (int i = 0; i < 8; i++) {
        const int m = m0 + ty * 8 + i;
        const int bb = m / rows_per_b;
        const int s = m - bb * rows_per_b;
        alignas(16) float o0[4], o1[4];
#pragma unroll
        for (int j = 0; j < 4; j++) {
            o0[j] = acc[i][j] + bias[n0 + tx * 4 + j];
            o1[j] = acc[i][4 + j] + bias[n0 + 64 + tx * 4 + j];
        }
        if (QKV_STORE) {
            // h = blockIdx.y (BN==DHEAD), d = tx*4 / 64+tx*4
            float* dst = C + (((size_t)bb * NHEADS + blockIdx.y) * S_TOT + s + C_s_off) * DHEAD;
            *(float4*)(dst + tx * 4) = *(float4*)o0;
            *(float4*)(dst + 64 + tx * 4) = *(float4*)o1;
        } else {
            float* dst = C + (size_t)m * D_MODEL + n0;
            *(float4*)(dst + tx * 4) = *(float4*)o0;
            *(float4*)(dst + 64 + tx * 4) = *(float4*)o1;
        }
    }
}

// ---------------------------------------------------------------------------
// RMSNorm (over DH=128) + RoPE, in place on q and k ([B][H][S][DH]).
// One wave per (b,h,s) row; lane t owns the rope pair (2t, 2t+1).
// gridDim.y: 0 -> q, 1 -> k.  4 rows per 256-thread block.
// ---------------------------------------------------------------------------
__global__ __launch_bounds__(256) void rmsrope_kernel(
    float* __restrict__ qbuf, float* __restrict__ kbuf,
    const float* __restrict__ gq, const float* __restrict__ gk,
    const float* __restrict__ gqa, const float* __restrict__ gka,
    const float* __restrict__ icos, const float* __restrict__ isin,
    const float* __restrict__ tcos, const float* __restrict__ tsin)
{
    const int t = threadIdx.x & 63;
    const int row = blockIdx.x * 4 + (threadIdx.x >> 6);  // (b*H + h)*S_TOT + s
    const int s = row % S_TOT;
    const bool is_img = s < S_IMGC;
    float* __restrict__ buf = blockIdx.y ? kbuf : qbuf;
    const float* __restrict__ g =
        blockIdx.y ? (is_img ? gk : gka) : (is_img ? gq : gqa);
    const int pos = is_img ? s : s - S_IMGC;
    const float* __restrict__ ct = (is_img ? icos : tcos) + pos * 64;
    const float* __restrict__ st = (is_img ? isin : tsin) + pos * 64;

    float* p = buf + (size_t)row * DHEAD + t * 2;
    float2 x = *(float2*)p;
    float ss = x.x * x.x + x.y * x.y;
#pragma unroll
    for (int off = 1; off < 64; off <<= 1) ss += __shfl_xor(ss, off, 64);
    const float r = rsqrtf(ss * (1.0f / DHEAD) + 1e-5f);
    const float y0 = x.x * r * g[t * 2];
    const float y1 = x.y * r * g[t * 2 + 1];
    const float c = ct[t], sn = st[t];
    float2 o;
    o.x = y0 * c - y1 * sn;
    o.y = y0 * sn + y1 * c;
    *(float2*)p = o;
}

// ---------------------------------------------------------------------------
// Flash attention, fp32.  Block = (q-tile 64) x (b,h).  256 threads (16x16),
// per thread: 4 q-rows (ty*4+i) x 4 k-cols (tx*4+j) of S; O cols tx*4 and
// 64+tx*4.  Online softmax; masked txt keys -> -1e9 (exp underflows to 0,
// matching the reference's additive -1e9 bias exactly in fp32).
// ---------------------------------------------------------------------------
__global__ __launch_bounds__(256) void attn_kernel(
    const float* __restrict__ qbuf, const float* __restrict__ kbuf,
    const float* __restrict__ vbuf, float* __restrict__ obuf,
    const int* __restrict__ mask)
{
    __shared__ float Qs[64][132];
    __shared__ float Ks[64][132];
    __shared__ float Vs[64][132];
    __shared__ float Ps[64][68];

    const int b = blockIdx.z, h = blockIdx.y;
    const int q0 = blockIdx.x * 64;
    const int tid = threadIdx.x;
    const int tx = tid & 15, ty = tid >> 4;
    const size_t head_base = ((size_t)b * NHEADS + h) * S_TOT * DHEAD;
    const float* __restrict__ qp = qbuf + head_base + (size_t)q0 * DHEAD;
    const float* __restrict__ kp = kbuf + head_base;
    const float* __restrict__ vp = vbuf + head_base;

#pragma unroll
    for (int i = 0; i < 8; i++) {
        const int f = i * 256 + tid;
        const int r = f >> 5, c4 = (f & 31) * 4;
        *(float4*)&Qs[r][c4] = *(const float4*)(qp + (size_t)r * DHEAD + c4);
    }

    float o[4][8];
    float mrow[4], lrow[4];
#pragma unroll
    for (int i = 0; i < 4; i++) {
        mrow[i] = -1e30f;
        lrow[i] = 0.f;
#pragma unroll
        for (int c = 0; c < 8; c++) o[i][c] = 0.f;
    }
    __syncthreads();

    for (int kt = 0; kt < S_TOT / 64; kt++) {
        const int k0 = kt * 64;
#pragma unroll
        for (int i = 0; i < 8; i++) {
            const int f = i * 256 + tid;
            const int r = f >> 5, c4 = (f & 31) * 4;
            *(float4*)&Ks[r][c4] = *(const float4*)(kp + (size_t)(k0 + r) * DHEAD + c4);
            *(float4*)&Vs[r][c4] = *(const float4*)(vp + (size_t)(k0 + r) * DHEAD + c4);
        }
        __syncthreads();

        // S = Q K^T (4x4 per thread)
        float sv[4][4];
#pragma unroll
        for (int i = 0; i < 4; i++)
#pragma unroll
            for (int j = 0; j < 4; j++) sv[i][j] = 0.f;
        for (int d4 = 0; d4 < 32; d4++) {
            float4 qv[4], kv[4];
#pragma unroll
            for (int i = 0; i < 4; i++) qv[i] = *(float4*)&Qs[ty * 4 + i][d4 * 4];
#pragma unroll
            for (int j = 0; j < 4; j++) kv[j] = *(float4*)&Ks[tx * 4 + j][d4 * 4];
#pragma unroll
            for (int i = 0; i < 4; i++)
#pragma unroll
                for (int j = 0; j < 4; j++)
                    sv[i][j] += qv[i].x * kv[j].x + qv[i].y * kv[j].y +
                                qv[i].z * kv[j].z + qv[i].w * kv[j].w;
        }
        // scale + key mask
#pragma unroll
        for (int j = 0; j < 4; j++) {
            const int kpix = k0 + tx * 4 + j;
            const bool valid =
                (kpix < S_IMGC) || (mask[b * S_TXTC + (kpix - S_IMGC)] != 0);
#pragma unroll
            for (int i = 0; i < 4; i++)
                sv[i][j] = valid ? sv[i][j] * ATT_SCALE : -1e9f;
        }
        // online softmax (reduce over the 16 tx lanes of each row)
#pragma unroll
        for (int i = 0; i < 4; i++) {
            float mloc = fmaxf(fmaxf(sv[i][0], sv[i][1]), fmaxf(sv[i][2], sv[i][3]));
#pragma unroll
            for (int off = 1; off < 16; off <<= 1)
                mloc = fmaxf(mloc, __shfl_xor(mloc, off, 64));
            const float mnew = fmaxf(mrow[i], mloc);
            const float alpha = __expf(mrow[i] - mnew);
            mrow[i] = mnew;
            float psum = 0.f;
#pragma unroll
            for (int j = 0; j < 4; j++) {
                const float pj = __expf(sv[i][j] - mnew);
                sv[i][j] = pj;
                psum += pj;
            }
#pragma unroll
            for (int off = 1; off < 16; off <<= 1) psum += __shfl_xor(psum, off, 64);
            lrow[i] = lrow[i] * alpha + psum;
#pragma unroll
            for (int c = 0; c < 8; c++) o[i][c] *= alpha;
        }
        // P -> LDS
#pragma unroll
        for (int i = 0; i < 4; i++) {
            alignas(16) float tmp[4] = {sv[i][0], sv[i][1], sv[i][2], sv[i][3]};
            *(float4*)&Ps[ty * 4 + i][tx * 4] = *(float4*)tmp;
        }
        __syncthreads();
        // O += P @ V
        for (int kk = 0; kk < 16; kk++) {
            float4 pv[4];
#pragma unroll
            for (int i = 0; i < 4; i++) pv[i] = *(float4*)&Ps[ty * 4 + i][kk * 4];
#pragma unroll
            for (int u = 0; u < 4; u++) {
                const float4 v0 = *(float4*)&Vs[kk * 4 + u][tx * 4];
                const float4 v1 = *(float4*)&Vs[kk * 4 + u][64 + tx * 4];
#pragma unroll
                for (int i = 0; i < 4; i++) {
                    const float p = (u == 0) ? pv[i].x : (u == 1) ? pv[i].y
                                  : (u == 2) ? pv[i].z : pv[i].w;
                    o[i][0] = fmaf(p, v0.x, o[i][0]);
                    o[i][1] = fmaf(p, v0.y, o[i][1]);
                    o[i][2] = fmaf(p, v0.z, o[i][2]);
                    o[i][3] = fmaf(p, v0.w, o[i][3]);
                    o[i][4] = fmaf(p, v1.x, o[i][4]);
                    o[i][5] = fmaf(p, v1.y, o[i][5]);
                    o[i][6] = fmaf(p, v1.z, o[i][6]);
                    o[i][7] = fmaf(p, v1.w, o[i][7]);
                }
            }
        }
        __syncthreads();  // before next K/V overwrite
    }

    // epilogue: normalize, write o as [B][S][H*DH]
#pragma unroll
    for (int i = 0; i < 4; i++) {
        const float inv = 1.0f / lrow[i];
        const int srow = q0 + ty * 4 + i;
        float* dst = obuf + ((size_t)b * S_TOT + srow) * D_MODEL + h * DHEAD;
        alignas(16) float w0[4], w1[4];
#pragma unroll
        for (int c = 0; c < 4; c++) {
            w0[c] = o[i][c] * inv;
            w1[c] = o[i][4 + c] * inv;
        }
        *(float4*)(dst + tx * 4) = *(float4*)w0;
        *(float4*)(dst + 64 + tx * 4) = *(float4*)w1;
    }
}

// ---------------------------------------------------------------------------
extern "C" void kernel_launch(void* const* d_in, const int* in_sizes, int n_in,
                              void* d_out, int out_size, void* d_ws, size_t ws_size,
                              hipStream_t stream)
{
    const float* hidden = (const float*)d_in[0];
    const float* enc    = (const float*)d_in[1];
    const int* encmask  = (const int*)d_in[2];
    // d_in[3] = txt_seq_lens (unused, always S_TXT)
    const float* icos = (const float*)d_in[4];
    const float* isin = (const float*)d_in[5];
    const float* tcos = (const float*)d_in[6];
    const float* tsin = (const float*)d_in[7];
    const float* wq  = (const float*)d_in[8];  const float* bq  = (const float*)d_in[9];
    const float* wk  = (const float*)d_in[10]; const float* bk  = (const float*)d_in[11];
    const float* wv  = (const float*)d_in[12]; const float* bv  = (const float*)d_in[13];
    const float* wqa = (const float*)d_in[14]; const float* bqa = (const float*)d_in[15];
    const float* wka = (const float*)d_in[16]; const float* bka = (const float*)d_in[17];
    const float* wva = (const float*)d_in[18]; const float* bva = (const float*)d_in[19];
    const float* wo  = (const float*)d_in[20]; const float* bo  = (const float*)d_in[21];
    const float* woa = (const float*)d_in[22]; const float* boa = (const float*)d_in[23];
    const float* gq  = (const float*)d_in[24]; const float* gk  = (const float*)d_in[25];
    const float* gqa = (const float*)d_in[26]; const float* gka = (const float*)d_in[27];
    float* out = (float*)d_out;

    const size_t NQKV = (size_t)BATCH * NHEADS * S_TOT * DHEAD;  // 14,155,776
    if (ws_size < 4 * NQKV * sizeof(float)) return;  // need 226.5 MB scratch
    float* q    = (float*)d_ws;
    float* kbuf = q + NQKV;
    float* vbuf = kbuf + NQKV;
    float* obuf = vbuf + NQKV;

    const dim3 blk(256);

    // img q/k/v projections: M = 4096, fused via grid.z
    gemm_kernel<true><<<dim3(32, 24, 3), blk, 0, stream>>>(
        hidden, (size_t)S_IMGC * D_MODEL, 0, S_IMGC,
        wq, wk, wv, bq, bk, bv, q, kbuf, vbuf, 0);
    // txt q/k/v projections: M = 512
    gemm_kernel<true><<<dim3(4, 24, 3), blk, 0, stream>>>(
        enc, (size_t)S_TXTC * D_MODEL, 0, S_TXTC,
        wqa, wka, wva, bqa, bka, bva, q, kbuf, vbuf, S_IMGC);

    // rmsnorm + rope on q,k (in place)
    rmsrope_kernel<<<dim3(BATCH * NHEADS * S_TOT / 4, 2), blk, 0, stream>>>(
        q, kbuf, gq, gk, gqa, gka, icos, isin, tcos, tsin);

    // attention
    attn_kernel<<<dim3(S_TOT / 64, NHEADS, BATCH), blk, 0, stream>>>(
        q, kbuf, vbuf, obuf, encmask);

    // output projections
    gemm_kernel<false><<<dim3(32, 24, 1), blk, 0, stream>>>(
        obuf, (size_t)S_TOT * D_MODEL, 0, S_IMGC,
        wo, wo, wo, bo, bo, bo, out, out, out, 0);
    gemm_kernel<false><<<dim3(4, 24, 1), blk, 0, stream>>>(
        obuf, (size_t)S_TOT * D_MODEL, S_IMGC, S_TXTC,
        woa, woa, woa, boa, boa, boa,
        out + (size_t)BATCH * S_IMGC * D_MODEL,
        out + (size_t)BATCH * S_IMGC * D_MODEL,
        out + (size_t)BATCH * S_IMGC * D_MODEL, 0);
}

// Round 2
// 2983.980 us; speedup vs baseline: 2.5133x; 2.5133x over previous
//
#include <hip/hip_runtime.h>
#include <cstdint>
#include <cstddef>

// ---------------------------------------------------------------------------
// QwenDoubleStreamAttention — round 2: bf16 MFMA GEMMs + conflict-free fp32
// attention with bf16 tiles.
//   B=2, S_img=2048, S_txt=256 (S=2304), D=3072, H=24, DH=128.
// Pipeline:
//   cvt_kernel       : hidden/enc fp32 -> bf16 row-major [m][3072]
//   transpose_w      : W fp32 [k][n] -> bf16 [n][k] (per-GEMM, reused slots)
//   gemm_bf16<true>  : MFMA qkv proj -> bf16 [B][H][S][DH], fused q/k/v via z
//   rmsrope_kernel   : RMSNorm + RoPE on q,k in place (bf16, fp32 math)
//   attn_kernel      : flash attention, fp32 compute from bf16 LDS tiles,
//                      k-col ownership tx+16j (conflict-free), out bf16
//   gemm_bf16<false> : MFMA out-proj -> d_out fp32
// Workspace: 198.2 MB (< 226.5 MB proven available).
// ---------------------------------------------------------------------------

#define D_MODEL 3072
#define NHEADS 24
#define DHEAD 128
#define S_IMGC 2048
#define S_TXTC 256
#define S_TOT 2304
#define BATCH 2
#define ATT_SCALE 0.08838834764831845f  // 128^-0.5

typedef __attribute__((ext_vector_type(8))) short short8;   // 8 bf16 = 4 VGPR
typedef __attribute__((ext_vector_type(4))) float f32x4;

__device__ __forceinline__ ushort f2bf(float f) {  // fp32 -> bf16 RNE
    uint u = __float_as_uint(f);
    return (ushort)((u + 0x7fffu + ((u >> 16) & 1u)) >> 16);
}
__device__ __forceinline__ float bf2f(ushort b) {
    return __uint_as_float(((uint)b) << 16);
}
// 4 consecutive bf16 at p (8B-aligned) -> 4 floats
__device__ __forceinline__ void bf4(const ushort* p, float* o) {
    uint2 u = *(const uint2*)p;
    o[0] = __uint_as_float(u.x << 16);
    o[1] = __uint_as_float(u.x & 0xffff0000u);
    o[2] = __uint_as_float(u.y << 16);
    o[3] = __uint_as_float(u.y & 0xffff0000u);
}

// ---------------------------------------------------------------------------
// fp32 -> bf16 elementwise (4 elems/thread)
// ---------------------------------------------------------------------------
__global__ __launch_bounds__(256) void cvt_kernel(
    const float* __restrict__ src, ushort* __restrict__ dst, int n4)
{
    int i = blockIdx.x * 256 + threadIdx.x;
    if (i >= n4) return;
    float4 v = ((const float4*)src)[i];
    ushort4 o;
    o.x = f2bf(v.x); o.y = f2bf(v.y); o.z = f2bf(v.z); o.w = f2bf(v.w);
    ((ushort4*)dst)[i] = o;
}

// ---------------------------------------------------------------------------
// W fp32 [k][n] -> bf16 [n][k].  64x64 LDS tile; grid.z picks weight.
// ---------------------------------------------------------------------------
__global__ __launch_bounds__(256) void transpose_w(
    const float* __restrict__ W0, const float* __restrict__ W1,
    const float* __restrict__ W2,
    ushort* __restrict__ T0, ushort* __restrict__ T1, ushort* __restrict__ T2)
{
    __shared__ float tile[64][68];
    const int z = blockIdx.z;
    const float* __restrict__ W = (z == 0) ? W0 : (z == 1) ? W1 : W2;
    ushort* __restrict__ T      = (z == 0) ? T0 : (z == 1) ? T1 : T2;
    const int tid = threadIdx.x;
    const int k0 = blockIdx.x * 64, n0 = blockIdx.y * 64;
    const int r = tid >> 4, c4 = (tid & 15) * 4;
#pragma unroll
    for (int i = 0; i < 4; i++) {
        float4 v = *(const float4*)(W + (size_t)(k0 + r + 16 * i) * D_MODEL + n0 + c4);
        *(float4*)&tile[r + 16 * i][c4] = v;
    }
    __syncthreads();
#pragma unroll
    for (int i = 0; i < 4; i++) {
        const int nn = n0 + r + 16 * i;
        ushort4 o;
        o.x = f2bf(tile[c4 + 0][r + 16 * i]);
        o.y = f2bf(tile[c4 + 1][r + 16 * i]);
        o.z = f2bf(tile[c4 + 2][r + 16 * i]);
        o.w = f2bf(tile[c4 + 3][r + 16 * i]);
        *(ushort4*)(T + (size_t)nn * D_MODEL + k0 + c4) = o;
    }
}

// ---------------------------------------------------------------------------
// MFMA GEMM: C = A @ W + bias, A bf16 [m][3072], Wt bf16 [n][3072] (= W^T).
// BM=BN=128, BK=32, 256 threads = 4 waves, each wave 4x4 16x16x32 tiles.
// Staging via global_load_lds width 16 (m97 structure, 2 barriers/K-iter).
// QKV_STORE: scatter bf16 to [B][H][S][DH] (h = blockIdx.y, BN==DHEAD);
// else fp32 row-major Cf[m][3072].
// ---------------------------------------------------------------------------
template <bool QKV_STORE>
__global__ __launch_bounds__(256) void gemm_bf16(
    const ushort* __restrict__ A, size_t A_bstride, int As_off, int rows_per_b,
    const ushort* __restrict__ B0, const ushort* __restrict__ B1,
    const ushort* __restrict__ B2,
    const float* __restrict__ bi0, const float* __restrict__ bi1,
    const float* __restrict__ bi2,
    ushort* __restrict__ Q0, ushort* __restrict__ Q1, ushort* __restrict__ Q2,
    float* __restrict__ Cf, int C_s_off)
{
    __shared__ ushort As[128 * 32];  // [m][k] packed, rows 64 B
    __shared__ ushort Bs[128 * 32];  // [n][k] packed

    const int z = blockIdx.z;
    const ushort* __restrict__ Wt  = (z == 0) ? B0 : (z == 1) ? B1 : B2;
    const float* __restrict__ bias = (z == 0) ? bi0 : (z == 1) ? bi1 : bi2;
    ushort* __restrict__ Cq        = (z == 0) ? Q0 : (z == 1) ? Q1 : Q2;

    const int tid = threadIdx.x;
    const int w = tid >> 6, lane = tid & 63;
    const int m0 = blockIdx.x * 128, n0 = blockIdx.y * 128;
    const int wm = w & 1, wn = w >> 1;

    // staging: wave w covers rows [w*32, w*32+32); 2 lds-DMA per operand
    const int ar0 = w * 32 + (lane >> 2);
    const int ar1 = ar0 + 16;
    const int acol = (lane & 3) * 8;  // ushort offset (16 B granule)
    const int ma0 = m0 + ar0, ma1 = m0 + ar1;
    const ushort* gA0 = A + (size_t)(ma0 / rows_per_b) * A_bstride +
                        (size_t)(ma0 % rows_per_b + As_off) * D_MODEL + acol;
    const ushort* gA1 = A + (size_t)(ma1 / rows_per_b) * A_bstride +
                        (size_t)(ma1 % rows_per_b + As_off) * D_MODEL + acol;
    const ushort* gB0 = Wt + (size_t)(n0 + ar0) * D_MODEL + acol;
    const ushort* gB1 = Wt + (size_t)(n0 + ar1) * D_MODEL + acol;
    ushort* lA0 = As + (w * 32) * 32;
    ushort* lA1 = As + (w * 32 + 16) * 32;
    ushort* lB0 = Bs + (w * 32) * 32;
    ushort* lB1 = Bs + (w * 32 + 16) * 32;

    f32x4 acc[4][4];
#pragma unroll
    for (int i = 0; i < 4; i++)
#pragma unroll
        for (int j = 0; j < 4; j++) acc[i][j] = (f32x4)0.f;

    const ushort* ap = As + (wm * 64 + (lane & 15)) * 32 + (lane >> 4) * 8;
    const ushort* bp = Bs + (wn * 64 + (lane & 15)) * 32 + (lane >> 4) * 8;

    for (int k0 = 0; k0 < D_MODEL; k0 += 32) {
        __syncthreads();  // all waves done reading previous tile
        __builtin_amdgcn_global_load_lds(
            (const __attribute__((address_space(1))) void*)(gA0 + k0),
            (__attribute__((address_space(3))) void*)lA0, 16, 0, 0);
        __builtin_amdgcn_global_load_lds(
            (const __attribute__((address_space(1))) void*)(gA1 + k0),
            (__attribute__((address_space(3))) void*)lA1, 16, 0, 0);
        __builtin_amdgcn_global_load_lds(
            (const __attribute__((address_space(1))) void*)(gB0 + k0),
            (__attribute__((address_space(3))) void*)lB0, 16, 0, 0);
        __builtin_amdgcn_global_load_lds(
            (const __attribute__((address_space(1))) void*)(gB1 + k0),
            (__attribute__((address_space(3))) void*)lB1, 16, 0, 0);
        __syncthreads();  // drains vmcnt(0): tiles visible

        short8 af[4], bf[4];
#pragma unroll
        for (int mt = 0; mt < 4; mt++) af[mt] = *(const short8*)(ap + mt * 512);
#pragma unroll
        for (int nt = 0; nt < 4; nt++) bf[nt] = *(const short8*)(bp + nt * 512);
#pragma unroll
        for (int mt = 0; mt < 4; mt++)
#pragma unroll
            for (int nt = 0; nt < 4; nt++)
                acc[mt][nt] = __builtin_amdgcn_mfma_f32_16x16x32_bf16(
                    af[mt], bf[nt], acc[mt][nt], 0, 0, 0);
    }

    // epilogue: C/D layout col=lane&15, row=(lane>>4)*4+reg
    const int col_loc = wn * 64 + (lane & 15);  // 0..127 within tile
    const int row_base = m0 + wm * 64 + (lane >> 4) * 4;
    float bv[4];
#pragma unroll
    for (int nt = 0; nt < 4; nt++) bv[nt] = bias[n0 + col_loc + nt * 16];
#pragma unroll
    for (int mt = 0; mt < 4; mt++) {
#pragma unroll
        for (int r = 0; r < 4; r++) {
            const int mm = row_base + mt * 16 + r;
            if (QKV_STORE) {
                const int bb = mm / rows_per_b;
                const int s = mm - bb * rows_per_b + C_s_off;
                ushort* dst = Cq + (((size_t)bb * NHEADS + blockIdx.y) * S_TOT + s) * DHEAD;
#pragma unroll
                for (int nt = 0; nt < 4; nt++)
                    dst[col_loc + nt * 16] = f2bf(acc[mt][nt][r] + bv[nt]);
            } else {
                float* dst = Cf + (size_t)mm * D_MODEL + n0;
#pragma unroll
                for (int nt = 0; nt < 4; nt++)
                    dst[col_loc + nt * 16] = acc[mt][nt][r] + bv[nt];
            }
        }
    }
}

// ---------------------------------------------------------------------------
// RMSNorm + RoPE in place on bf16 q/k ([B][H][S][DH]).  Wave per row.
// ---------------------------------------------------------------------------
__global__ __launch_bounds__(256) void rmsrope_kernel(
    ushort* __restrict__ qbuf, ushort* __restrict__ kbuf,
    const float* __restrict__ gq, const float* __restrict__ gk,
    const float* __restrict__ gqa, const float* __restrict__ gka,
    const float* __restrict__ icos, const float* __restrict__ isin,
    const float* __restrict__ tcos, const float* __restrict__ tsin)
{
    const int t = threadIdx.x & 63;
    const int row = blockIdx.x * 4 + (threadIdx.x >> 6);  // (b*H+h)*S_TOT + s
    const int s = row % S_TOT;
    const bool is_img = s < S_IMGC;
    ushort* __restrict__ buf = blockIdx.y ? kbuf : qbuf;
    const float* __restrict__ g =
        blockIdx.y ? (is_img ? gk : gka) : (is_img ? gq : gqa);
    const int pos = is_img ? s : s - S_IMGC;
    const float* __restrict__ ct = (is_img ? icos : tcos) + pos * 64;
    const float* __restrict__ st = (is_img ? isin : tsin) + pos * 64;

    ushort* p = buf + (size_t)row * DHEAD + t * 2;
    uint u = *(uint*)p;
    const float x0 = __uint_as_float(u << 16);
    const float x1 = __uint_as_float(u & 0xffff0000u);
    float ss = x0 * x0 + x1 * x1;
#pragma unroll
    for (int off = 1; off < 64; off <<= 1) ss += __shfl_xor(ss, off, 64);
    const float r = rsqrtf(ss * (1.0f / DHEAD) + 1e-5f);
    const float y0 = x0 * r * g[t * 2];
    const float y1 = x1 * r * g[t * 2 + 1];
    const float c = ct[t], sn = st[t];
    const float o0 = y0 * c - y1 * sn;
    const float o1 = y0 * sn + y1 * c;
    *(uint*)p = (uint)f2bf(o0) | ((uint)f2bf(o1) << 16);
}

// ---------------------------------------------------------------------------
// Flash attention: bf16 q/k/v tiles in LDS, fp32 compute, bf16 out.
// 256 threads (tx 0..15, ty 0..15); per thread 4 q-rows (ty*4+i),
// 4 k-cols (tx+16j  <- conflict-free mapping), O cols tx*4 / 64+tx*4.
// LDS 68 KB -> 2 blocks/CU.
// ---------------------------------------------------------------------------
__global__ __launch_bounds__(256) void attn_kernel(
    const ushort* __restrict__ qb, const ushort* __restrict__ kb,
    const ushort* __restrict__ vb, ushort* __restrict__ ob,
    const int* __restrict__ mask)
{
    __shared__ ushort Qs[64 * 136];  // rows padded to 272 B (16B-aligned)
    __shared__ ushort Ks[64 * 136];
    __shared__ ushort Vs[64 * 136];
    __shared__ float Ps[64 * 68];

    const int b = blockIdx.z, h = blockIdx.y;
    const int q0 = blockIdx.x * 64;
    const int tid = threadIdx.x;
    const int tx = tid & 15, ty = tid >> 4;
    const size_t hb = ((size_t)b * NHEADS + h) * S_TOT * DHEAD;
    const ushort* qp = qb + hb + (size_t)q0 * DHEAD;
    const ushort* kp = kb + hb;
    const ushort* vp = vb + hb;

#pragma unroll
    for (int i = 0; i < 4; i++) {
        const int f = i * 256 + tid;
        const int r = f >> 4, c = (f & 15) * 8;
        *(uint4*)(Qs + r * 136 + c) = *(const uint4*)(qp + r * DHEAD + c);
    }

    float o[4][8], mrow[4], lrow[4];
#pragma unroll
    for (int i = 0; i < 4; i++) {
        mrow[i] = -1e30f;
        lrow[i] = 0.f;
#pragma unroll
        for (int c = 0; c < 8; c++) o[i][c] = 0.f;
    }
    __syncthreads();

    for (int kt = 0; kt < S_TOT / 64; kt++) {
        const int k0 = kt * 64;
#pragma unroll
        for (int i = 0; i < 4; i++) {
            const int f = i * 256 + tid;
            const int r = f >> 4, c = (f & 15) * 8;
            *(uint4*)(Ks + r * 136 + c) = *(const uint4*)(kp + (size_t)(k0 + r) * DHEAD + c);
            *(uint4*)(Vs + r * 136 + c) = *(const uint4*)(vp + (size_t)(k0 + r) * DHEAD + c);
        }
        __syncthreads();

        float sv[4][4];
#pragma unroll
        for (int i = 0; i < 4; i++)
#pragma unroll
            for (int j = 0; j < 4; j++) sv[i][j] = 0.f;
        for (int d4 = 0; d4 < 32; d4++) {
            float qv[4][4], kv[4][4];
#pragma unroll
            for (int i = 0; i < 4; i++) bf4(Qs + (ty * 4 + i) * 136 + d4 * 4, qv[i]);
#pragma unroll
            for (int j = 0; j < 4; j++) bf4(Ks + (tx + 16 * j) * 136 + d4 * 4, kv[j]);
#pragma unroll
            for (int i = 0; i < 4; i++)
#pragma unroll
                for (int j = 0; j < 4; j++)
                    sv[i][j] += qv[i][0] * kv[j][0] + qv[i][1] * kv[j][1] +
                                qv[i][2] * kv[j][2] + qv[i][3] * kv[j][3];
        }
#pragma unroll
        for (int j = 0; j < 4; j++) {
            const int col = k0 + tx + 16 * j;
            const bool valid =
                (col < S_IMGC) || (mask[b * S_TXTC + (col - S_IMGC)] != 0);
#pragma unroll
            for (int i = 0; i < 4; i++)
                sv[i][j] = valid ? sv[i][j] * ATT_SCALE : -1e9f;
        }
#pragma unroll
        for (int i = 0; i < 4; i++) {
            float mloc = fmaxf(fmaxf(sv[i][0], sv[i][1]), fmaxf(sv[i][2], sv[i][3]));
#pragma unroll
            for (int off = 1; off < 16; off <<= 1)
                mloc = fmaxf(mloc, __shfl_xor(mloc, off, 64));
            const float mnew = fmaxf(mrow[i], mloc);
            const float alpha = __expf(mrow[i] - mnew);
            mrow[i] = mnew;
            float psum = 0.f;
#pragma unroll
            for (int j = 0; j < 4; j++) {
                const float pj = __expf(sv[i][j] - mnew);
                sv[i][j] = pj;
                psum += pj;
            }
#pragma unroll
            for (int off = 1; off < 16; off <<= 1) psum += __shfl_xor(psum, off, 64);
            lrow[i] = lrow[i] * alpha + psum;
#pragma unroll
            for (int c = 0; c < 8; c++) o[i][c] *= alpha;
        }
#pragma unroll
        for (int i = 0; i < 4; i++)
#pragma unroll
            for (int j = 0; j < 4; j++)
                Ps[(ty * 4 + i) * 68 + tx + 16 * j] = sv[i][j];
        __syncthreads();

        for (int kk = 0; kk < 16; kk++) {
            float4 pv[4];
#pragma unroll
            for (int i = 0; i < 4; i++) pv[i] = *(float4*)(Ps + (ty * 4 + i) * 68 + kk * 4);
#pragma unroll
            for (int u = 0; u < 4; u++) {
                float v0[4], v1[4];
                bf4(Vs + (kk * 4 + u) * 136 + tx * 4, v0);
                bf4(Vs + (kk * 4 + u) * 136 + 64 + tx * 4, v1);
#pragma unroll
                for (int i = 0; i < 4; i++) {
                    const float p = (u == 0) ? pv[i].x : (u == 1) ? pv[i].y
                                  : (u == 2) ? pv[i].z : pv[i].w;
                    o[i][0] = fmaf(p, v0[0], o[i][0]);
                    o[i][1] = fmaf(p, v0[1], o[i][1]);
                    o[i][2] = fmaf(p, v0[2], o[i][2]);
                    o[i][3] = fmaf(p, v0[3], o[i][3]);
                    o[i][4] = fmaf(p, v1[0], o[i][4]);
                    o[i][5] = fmaf(p, v1[1], o[i][5]);
                    o[i][6] = fmaf(p, v1[2], o[i][6]);
                    o[i][7] = fmaf(p, v1[3], o[i][7]);
                }
            }
        }
        __syncthreads();
    }

#pragma unroll
    for (int i = 0; i < 4; i++) {
        const float inv = 1.0f / lrow[i];
        const int srow = q0 + ty * 4 + i;
        ushort* dst = ob + ((size_t)b * S_TOT + srow) * D_MODEL + h * DHEAD;
        ushort4 w0, w1;
        w0.x = f2bf(o[i][0] * inv); w0.y = f2bf(o[i][1] * inv);
        w0.z = f2bf(o[i][2] * inv); w0.w = f2bf(o[i][3] * inv);
        w1.x = f2bf(o[i][4] * inv); w1.y = f2bf(o[i][5] * inv);
        w1.z = f2bf(o[i][6] * inv); w1.w = f2bf(o[i][7] * inv);
        *(ushort4*)(dst + tx * 4) = w0;
        *(ushort4*)(dst + 64 + tx * 4) = w1;
    }
}

// ---------------------------------------------------------------------------
extern "C" void kernel_launch(void* const* d_in, const int* in_sizes, int n_in,
                              void* d_out, int out_size, void* d_ws, size_t ws_size,
                              hipStream_t stream)
{
    const float* hidden = (const float*)d_in[0];
    const float* enc    = (const float*)d_in[1];
    const int* encmask  = (const int*)d_in[2];
    const float* icos = (const float*)d_in[4];
    const float* isin = (const float*)d_in[5];
    const float* tcos = (const float*)d_in[6];
    const float* tsin = (const float*)d_in[7];
    const float* wq  = (const float*)d_in[8];  const float* bq  = (const float*)d_in[9];
    const float* wk  = (const float*)d_in[10]; const float* bk  = (const float*)d_in[11];
    const float* wv  = (const float*)d_in[12]; const float* bv  = (const float*)d_in[13];
    const float* wqa = (const float*)d_in[14]; const float* bqa = (const float*)d_in[15];
    const float* wka = (const float*)d_in[16]; const float* bka = (const float*)d_in[17];
    const float* wva = (const float*)d_in[18]; const float* bva = (const float*)d_in[19];
    const float* wo  = (const float*)d_in[20]; const float* bo  = (const float*)d_in[21];
    const float* woa = (const float*)d_in[22]; const float* boa = (const float*)d_in[23];
    const float* gq  = (const float*)d_in[24]; const float* gk  = (const float*)d_in[25];
    const float* gqa = (const float*)d_in[26]; const float* gka = (const float*)d_in[27];
    float* out = (float*)d_out;

    // workspace layout (bytes)
    const size_t W_ELE = (size_t)D_MODEL * D_MODEL;               // 9,437,184
    const size_t NQKV  = (size_t)BATCH * NHEADS * S_TOT * DHEAD;  // 14,155,776
    char* p = (char*)d_ws;
    ushort* wT0 = (ushort*)p; p += W_ELE * 2;
    ushort* wT1 = (ushort*)p; p += W_ELE * 2;
    ushort* wT2 = (ushort*)p; p += W_ELE * 2;
    ushort* ximg = (ushort*)p; p += (size_t)BATCH * S_IMGC * D_MODEL * 2;
    ushort* xtxt = (ushort*)p; p += (size_t)BATCH * S_TXTC * D_MODEL * 2;
    ushort* qbuf = (ushort*)p; p += NQKV * 2;
    ushort* kbuf = (ushort*)p; p += NQKV * 2;
    ushort* vbuf = (ushort*)p; p += NQKV * 2;
    ushort* obuf = (ushort*)p; p += (size_t)BATCH * S_TOT * D_MODEL * 2;
    if ((size_t)(p - (char*)d_ws) > ws_size) return;  // 198.2 MB needed

    const dim3 blk(256);

    // activations -> bf16
    cvt_kernel<<<dim3((BATCH * S_IMGC * D_MODEL / 4 + 255) / 256), blk, 0, stream>>>(
        hidden, ximg, BATCH * S_IMGC * D_MODEL / 4);
    cvt_kernel<<<dim3((BATCH * S_TXTC * D_MODEL / 4 + 255) / 256), blk, 0, stream>>>(
        enc, xtxt, BATCH * S_TXTC * D_MODEL / 4);

    // img qkv
    transpose_w<<<dim3(48, 48, 3), blk, 0, stream>>>(wq, wk, wv, wT0, wT1, wT2);
    gemm_bf16<true><<<dim3(32, 24, 3), blk, 0, stream>>>(
        ximg, (size_t)S_IMGC * D_MODEL, 0, S_IMGC,
        wT0, wT1, wT2, bq, bk, bv, qbuf, kbuf, vbuf, nullptr, 0);
    // txt qkv
    transpose_w<<<dim3(48, 48, 3), blk, 0, stream>>>(wqa, wka, wva, wT0, wT1, wT2);
    gemm_bf16<true><<<dim3(4, 24, 3), blk, 0, stream>>>(
        xtxt, (size_t)S_TXTC * D_MODEL, 0, S_TXTC,
        wT0, wT1, wT2, bqa, bka, bva, qbuf, kbuf, vbuf, nullptr, S_IMGC);

    // rmsnorm + rope
    rmsrope_kernel<<<dim3(BATCH * NHEADS * S_TOT / 4, 2), blk, 0, stream>>>(
        qbuf, kbuf, gq, gk, gqa, gka, icos, isin, tcos, tsin);

    // attention
    attn_kernel<<<dim3(S_TOT / 64, NHEADS, BATCH), blk, 0, stream>>>(
        qbuf, kbuf, vbuf, obuf, encmask);

    // out-proj img
    transpose_w<<<dim3(48, 48, 1), blk, 0, stream>>>(wo, wo, wo, wT0, wT0, wT0);
    gemm_bf16<false><<<dim3(32, 24, 1), blk, 0, stream>>>(
        obuf, (size_t)S_TOT * D_MODEL, 0, S_IMGC,
        wT0, wT0, wT0, bo, bo, bo, nullptr, nullptr, nullptr, out, 0);
    // out-proj txt
    transpose_w<<<dim3(48, 48, 1), blk, 0, stream>>>(woa, woa, woa, wT0, wT0, wT0);
    gemm_bf16<false><<<dim3(4, 24, 1), blk, 0, stream>>>(
        obuf, (size_t)S_TOT * D_MODEL, S_IMGC, S_TXTC,
        wT0, wT0, wT0, boa, boa, boa, nullptr, nullptr, nullptr,
        out + (size_t)BATCH * S_IMGC * D_MODEL, 0);
}

// Round 3
// 1576.085 us; speedup vs baseline: 4.7583x; 1.8933x over previous
//
#include <hip/hip_runtime.h>
#include <cstdint>
#include <cstddef>

// ---------------------------------------------------------------------------
// QwenDoubleStreamAttention — round 3: MFMA flash attention.
//   B=2, S_img=2048, S_txt=256 (S=2304), D=3072, H=24, DH=128.
// Pipeline:
//   cvt_kernel       : hidden/enc fp32 -> bf16
//   transpose_w      : W fp32 [k][n] -> bf16 [n][k]
//   gemm_bf16<true>  : MFMA qkv proj -> bf16 [B][H][S][DH]
//   rmsrope_kernel   : RMSNorm + RoPE on q,k in place
//   transpose_v      : V [B][H][S][DH] -> Vt [B][H][DH][S]
//   attn_kernel      : MFMA flash attention (16x16x32 bf16), 128 q-rows/block,
//                      64-key tiles, P via per-wave-private LDS (bf16),
//                      register-prefetch K/Vt staging, 2 barriers/tile.
//   gemm_bf16<false> : MFMA out-proj -> d_out fp32
// Workspace: 226,492,416 B (exactly the round-1 budget, proven available).
// ---------------------------------------------------------------------------

#define D_MODEL 3072
#define NHEADS 24
#define DHEAD 128
#define S_IMGC 2048
#define S_TXTC 256
#define S_TOT 2304
#define BATCH 2
#define ATT_SCALE 0.08838834764831845f  // 128^-0.5

typedef __attribute__((ext_vector_type(8))) short short8;   // 8 bf16 = 4 VGPR
typedef __attribute__((ext_vector_type(4))) float f32x4;

__device__ __forceinline__ ushort f2bf(float f) {  // fp32 -> bf16 RNE
    uint u = __float_as_uint(f);
    return (ushort)((u + 0x7fffu + ((u >> 16) & 1u)) >> 16);
}

// ---------------------------------------------------------------------------
__global__ __launch_bounds__(256) void cvt_kernel(
    const float* __restrict__ src, ushort* __restrict__ dst, int n4)
{
    int i = blockIdx.x * 256 + threadIdx.x;
    if (i >= n4) return;
    float4 v = ((const float4*)src)[i];
    ushort4 o;
    o.x = f2bf(v.x); o.y = f2bf(v.y); o.z = f2bf(v.z); o.w = f2bf(v.w);
    ((ushort4*)dst)[i] = o;
}

// ---------------------------------------------------------------------------
// W fp32 [k][n] -> bf16 [n][k].  64x64 LDS tile; grid.z picks weight.
// ---------------------------------------------------------------------------
__global__ __launch_bounds__(256) void transpose_w(
    const float* __restrict__ W0, const float* __restrict__ W1,
    const float* __restrict__ W2,
    ushort* __restrict__ T0, ushort* __restrict__ T1, ushort* __restrict__ T2)
{
    __shared__ float tile[64][68];
    const int z = blockIdx.z;
    const float* __restrict__ W = (z == 0) ? W0 : (z == 1) ? W1 : W2;
    ushort* __restrict__ T      = (z == 0) ? T0 : (z == 1) ? T1 : T2;
    const int tid = threadIdx.x;
    const int k0 = blockIdx.x * 64, n0 = blockIdx.y * 64;
    const int r = tid >> 4, c4 = (tid & 15) * 4;
#pragma unroll
    for (int i = 0; i < 4; i++) {
        float4 v = *(const float4*)(W + (size_t)(k0 + r + 16 * i) * D_MODEL + n0 + c4);
        *(float4*)&tile[r + 16 * i][c4] = v;
    }
    __syncthreads();
#pragma unroll
    for (int i = 0; i < 4; i++) {
        const int nn = n0 + r + 16 * i;
        ushort4 o;
        o.x = f2bf(tile[c4 + 0][r + 16 * i]);
        o.y = f2bf(tile[c4 + 1][r + 16 * i]);
        o.z = f2bf(tile[c4 + 2][r + 16 * i]);
        o.w = f2bf(tile[c4 + 3][r + 16 * i]);
        *(ushort4*)(T + (size_t)nn * D_MODEL + k0 + c4) = o;
    }
}

// ---------------------------------------------------------------------------
// V bf16 [B][H][S][DH] -> Vt bf16 [B][H][DH][S].  64x64 tiles.
// ---------------------------------------------------------------------------
__global__ __launch_bounds__(256) void transpose_v(
    const ushort* __restrict__ v, ushort* __restrict__ vt)
{
    __shared__ ushort t[64][72];
    const int bh = blockIdx.z;
    const int s0 = blockIdx.x * 64, d0 = blockIdx.y * 64;
    const size_t base  = (size_t)bh * S_TOT * DHEAD;
    const size_t baset = (size_t)bh * DHEAD * S_TOT;
    const int tid = threadIdx.x;
#pragma unroll
    for (int i = 0; i < 2; i++) {
        int id = tid + 256 * i;
        int r = id >> 3, c = (id & 7) * 8;
        *(uint4*)&t[r][c] = *(const uint4*)(v + base + (size_t)(s0 + r) * DHEAD + d0 + c);
    }
    __syncthreads();
#pragma unroll
    for (int i = 0; i < 2; i++) {
        int id = tid + 256 * i;
        int r = id >> 3, c = (id & 7) * 8;  // r = dh_loc, c = s chunk base
        ushort tmp[8];
#pragma unroll
        for (int j = 0; j < 8; j++) tmp[j] = t[c + j][r];
        *(uint4*)(vt + baset + (size_t)(d0 + r) * S_TOT + s0 + c) = *(uint4*)tmp;
    }
}

// ---------------------------------------------------------------------------
// MFMA GEMM (round-2 structure, unchanged).
// ---------------------------------------------------------------------------
template <bool QKV_STORE>
__global__ __launch_bounds__(256) void gemm_bf16(
    const ushort* __restrict__ A, size_t A_bstride, int As_off, int rows_per_b,
    const ushort* __restrict__ B0, const ushort* __restrict__ B1,
    const ushort* __restrict__ B2,
    const float* __restrict__ bi0, const float* __restrict__ bi1,
    const float* __restrict__ bi2,
    ushort* __restrict__ Q0, ushort* __restrict__ Q1, ushort* __restrict__ Q2,
    float* __restrict__ Cf, int C_s_off)
{
    __shared__ ushort As[128 * 32];
    __shared__ ushort Bs[128 * 32];

    const int z = blockIdx.z;
    const ushort* __restrict__ Wt  = (z == 0) ? B0 : (z == 1) ? B1 : B2;
    const float* __restrict__ bias = (z == 0) ? bi0 : (z == 1) ? bi1 : bi2;
    ushort* __restrict__ Cq        = (z == 0) ? Q0 : (z == 1) ? Q1 : Q2;

    const int tid = threadIdx.x;
    const int w = tid >> 6, lane = tid & 63;
    const int m0 = blockIdx.x * 128, n0 = blockIdx.y * 128;
    const int wm = w & 1, wn = w >> 1;

    const int ar0 = w * 32 + (lane >> 2);
    const int ar1 = ar0 + 16;
    const int acol = (lane & 3) * 8;
    const int ma0 = m0 + ar0, ma1 = m0 + ar1;
    const ushort* gA0 = A + (size_t)(ma0 / rows_per_b) * A_bstride +
                        (size_t)(ma0 % rows_per_b + As_off) * D_MODEL + acol;
    const ushort* gA1 = A + (size_t)(ma1 / rows_per_b) * A_bstride +
                        (size_t)(ma1 % rows_per_b + As_off) * D_MODEL + acol;
    const ushort* gB0 = Wt + (size_t)(n0 + ar0) * D_MODEL + acol;
    const ushort* gB1 = Wt + (size_t)(n0 + ar1) * D_MODEL + acol;
    ushort* lA0 = As + (w * 32) * 32;
    ushort* lA1 = As + (w * 32 + 16) * 32;
    ushort* lB0 = Bs + (w * 32) * 32;
    ushort* lB1 = Bs + (w * 32 + 16) * 32;

    f32x4 acc[4][4];
#pragma unroll
    for (int i = 0; i < 4; i++)
#pragma unroll
        for (int j = 0; j < 4; j++) acc[i][j] = (f32x4)0.f;

    const ushort* ap = As + (wm * 64 + (lane & 15)) * 32 + (lane >> 4) * 8;
    const ushort* bp = Bs + (wn * 64 + (lane & 15)) * 32 + (lane >> 4) * 8;

    for (int k0 = 0; k0 < D_MODEL; k0 += 32) {
        __syncthreads();
        __builtin_amdgcn_global_load_lds(
            (const __attribute__((address_space(1))) void*)(gA0 + k0),
            (__attribute__((address_space(3))) void*)lA0, 16, 0, 0);
        __builtin_amdgcn_global_load_lds(
            (const __attribute__((address_space(1))) void*)(gA1 + k0),
            (__attribute__((address_space(3))) void*)lA1, 16, 0, 0);
        __builtin_amdgcn_global_load_lds(
            (const __attribute__((address_space(1))) void*)(gB0 + k0),
            (__attribute__((address_space(3))) void*)lB0, 16, 0, 0);
        __builtin_amdgcn_global_load_lds(
            (const __attribute__((address_space(1))) void*)(gB1 + k0),
            (__attribute__((address_space(3))) void*)lB1, 16, 0, 0);
        __syncthreads();

        short8 af[4], bf[4];
#pragma unroll
        for (int mt = 0; mt < 4; mt++) af[mt] = *(const short8*)(ap + mt * 512);
#pragma unroll
        for (int nt = 0; nt < 4; nt++) bf[nt] = *(const short8*)(bp + nt * 512);
#pragma unroll
        for (int mt = 0; mt < 4; mt++)
#pragma unroll
            for (int nt = 0; nt < 4; nt++)
                acc[mt][nt] = __builtin_amdgcn_mfma_f32_16x16x32_bf16(
                    af[mt], bf[nt], acc[mt][nt], 0, 0, 0);
    }

    const int col_loc = wn * 64 + (lane & 15);
    const int row_base = m0 + wm * 64 + (lane >> 4) * 4;
    float bv[4];
#pragma unroll
    for (int nt = 0; nt < 4; nt++) bv[nt] = bias[n0 + col_loc + nt * 16];
#pragma unroll
    for (int mt = 0; mt < 4; mt++) {
#pragma unroll
        for (int r = 0; r < 4; r++) {
            const int mm = row_base + mt * 16 + r;
            if (QKV_STORE) {
                const int bb = mm / rows_per_b;
                const int s = mm - bb * rows_per_b + C_s_off;
                ushort* dst = Cq + (((size_t)bb * NHEADS + blockIdx.y) * S_TOT + s) * DHEAD;
#pragma unroll
                for (int nt = 0; nt < 4; nt++)
                    dst[col_loc + nt * 16] = f2bf(acc[mt][nt][r] + bv[nt]);
            } else {
                float* dst = Cf + (size_t)mm * D_MODEL + n0;
#pragma unroll
                for (int nt = 0; nt < 4; nt++)
                    dst[col_loc + nt * 16] = acc[mt][nt][r] + bv[nt];
            }
        }
    }
}

// ---------------------------------------------------------------------------
// RMSNorm + RoPE in place on bf16 q/k ([B][H][S][DH]).  Wave per row.
// ---------------------------------------------------------------------------
__global__ __launch_bounds__(256) void rmsrope_kernel(
    ushort* __restrict__ qbuf, ushort* __restrict__ kbuf,
    const float* __restrict__ gq, const float* __restrict__ gk,
    const float* __restrict__ gqa, const float* __restrict__ gka,
    const float* __restrict__ icos, const float* __restrict__ isin,
    const float* __restrict__ tcos, const float* __restrict__ tsin)
{
    const int t = threadIdx.x & 63;
    const int row = blockIdx.x * 4 + (threadIdx.x >> 6);
    const int s = row % S_TOT;
    const bool is_img = s < S_IMGC;
    ushort* __restrict__ buf = blockIdx.y ? kbuf : qbuf;
    const float* __restrict__ g =
        blockIdx.y ? (is_img ? gk : gka) : (is_img ? gq : gqa);
    const int pos = is_img ? s : s - S_IMGC;
    const float* __restrict__ ct = (is_img ? icos : tcos) + pos * 64;
    const float* __restrict__ st = (is_img ? isin : tsin) + pos * 64;

    ushort* p = buf + (size_t)row * DHEAD + t * 2;
    uint u = *(uint*)p;
    const float x0 = __uint_as_float(u << 16);
    const float x1 = __uint_as_float(u & 0xffff0000u);
    float ss = x0 * x0 + x1 * x1;
#pragma unroll
    for (int off = 1; off < 64; off <<= 1) ss += __shfl_xor(ss, off, 64);
    const float r = rsqrtf(ss * (1.0f / DHEAD) + 1e-5f);
    const float y0 = x0 * r * g[t * 2];
    const float y1 = x1 * r * g[t * 2 + 1];
    const float c = ct[t], sn = st[t];
    const float o0 = y0 * c - y1 * sn;
    const float o1 = y0 * sn + y1 * c;
    *(uint*)p = (uint)f2bf(o0) | ((uint)f2bf(o1) << 16);
}

// ---------------------------------------------------------------------------
// MFMA flash attention.  256 threads = 4 waves; block = 128 q-rows; wave owns
// 32 rows (2 m-tiles).  K-tile = 64 keys.  16x16x32 bf16 MFMA throughout.
//   QK^T: A = Q frags (regs, preloaded), B-frag lane: key=n0+(lane&15),
//         dh=(lane>>4)*8+j  -> contiguous b128 from Ks[key][dh].
//   PV  : A = P (bf16, per-wave-private LDS rows -> no barrier), B-frag lane:
//         dh=n0+(lane&15), key=(lane>>4)*8+j -> contiguous b128 from Vt[dh][key].
// Register-prefetch of next K/Vt tile; 2 barriers per tile.  LDS 54.3 KB.
// ---------------------------------------------------------------------------
__global__ __launch_bounds__(256) void attn_kernel(
    const ushort* __restrict__ qb, const ushort* __restrict__ kb,
    const ushort* __restrict__ vtb, ushort* __restrict__ ob,
    const int* __restrict__ maskp)
{
    __shared__ ushort Ks[64 * 136];   // [key][dh], row stride 136 (16B-aligned)
    __shared__ ushort Vts[128 * 72];  // [dh][key], row stride 72
    __shared__ ushort Ps[128 * 72];   // [qrow][key] bf16, per-wave rows

    const int b = blockIdx.z, h = blockIdx.y;
    const int q0 = blockIdx.x * 128;
    const int tid = threadIdx.x;
    const int w = tid >> 6, lane = tid & 63;
    const int l = lane & 15, quad = lane >> 4;
    const size_t hb  = ((size_t)b * NHEADS + h) * S_TOT * DHEAD;
    const size_t hbt = ((size_t)b * NHEADS + h) * DHEAD * S_TOT;
    const ushort* kp  = kb + hb;
    const ushort* vtp = vtb + hbt;

    // Q fragments (regs): [mt][kstep]; A-layout m=lane&15, k=quad*8+j
    short8 qf[2][4];
#pragma unroll
    for (int mt = 0; mt < 2; mt++)
#pragma unroll
        for (int kf = 0; kf < 4; kf++)
            qf[mt][kf] = *(const short8*)(qb + hb +
                (size_t)(q0 + w * 32 + mt * 16 + l) * DHEAD + kf * 32 + quad * 8);

    f32x4 o_acc[2][8];
    float mrow[2][4], lrow[2][4];
#pragma unroll
    for (int mt = 0; mt < 2; mt++) {
#pragma unroll
        for (int nt = 0; nt < 8; nt++) o_acc[mt][nt] = (f32x4)0.f;
#pragma unroll
        for (int r = 0; r < 4; r++) { mrow[mt][r] = -1e30f; lrow[mt][r] = 0.f; }
    }

    // prefetch tile 0 into regs
    uint4 kpre[4], vpre[4];
#pragma unroll
    for (int i = 0; i < 4; i++) {
        const int id = tid + 256 * i;
        kpre[i] = *(const uint4*)(kp + (size_t)(id >> 4) * DHEAD + (id & 15) * 8);
        vpre[i] = *(const uint4*)(vtp + (size_t)(id >> 3) * S_TOT + (id & 7) * 8);
    }

    for (int kt = 0; kt < S_TOT / 64; kt++) {
        const int k0 = kt * 64;
        __syncthreads();  // everyone done reading previous Ks/Vts
#pragma unroll
        for (int i = 0; i < 4; i++) {
            const int id = tid + 256 * i;
            *(uint4*)&Ks[(id >> 4) * 136 + (id & 15) * 8] = kpre[i];
            *(uint4*)&Vts[(id >> 3) * 72 + (id & 7) * 8] = vpre[i];
        }
        if (kt + 1 < S_TOT / 64) {
            const int k0n = k0 + 64;
#pragma unroll
            for (int i = 0; i < 4; i++) {
                const int id = tid + 256 * i;
                kpre[i] = *(const uint4*)(kp + (size_t)(k0n + (id >> 4)) * DHEAD + (id & 15) * 8);
                vpre[i] = *(const uint4*)(vtp + (size_t)(id >> 3) * S_TOT + k0n + (id & 7) * 8);
            }
        }
        __syncthreads();  // tiles visible

        // ---- S = Q K^T
        f32x4 sa[2][4];
#pragma unroll
        for (int mt = 0; mt < 2; mt++)
#pragma unroll
            for (int nt = 0; nt < 4; nt++) sa[mt][nt] = (f32x4)0.f;
#pragma unroll
        for (int ks = 0; ks < 4; ks++) {
            short8 kfr[4];
#pragma unroll
            for (int nt = 0; nt < 4; nt++)
                kfr[nt] = *(const short8*)&Ks[(nt * 16 + l) * 136 + ks * 32 + quad * 8];
#pragma unroll
            for (int mt = 0; mt < 2; mt++)
#pragma unroll
                for (int nt = 0; nt < 4; nt++)
                    sa[mt][nt] = __builtin_amdgcn_mfma_f32_16x16x32_bf16(
                        qf[mt][ks], kfr[nt], sa[mt][nt], 0, 0, 0);
        }

        // ---- scale + mask
#pragma unroll
        for (int mt = 0; mt < 2; mt++)
#pragma unroll
            for (int nt = 0; nt < 4; nt++)
#pragma unroll
                for (int r = 0; r < 4; r++) sa[mt][nt][r] *= ATT_SCALE;
        if (k0 >= S_IMGC) {
#pragma unroll
            for (int nt = 0; nt < 4; nt++) {
                const bool valid =
                    maskp[b * S_TXTC + k0 - S_IMGC + nt * 16 + l] != 0;
#pragma unroll
                for (int mt = 0; mt < 2; mt++)
#pragma unroll
                    for (int r = 0; r < 4; r++)
                        sa[mt][nt][r] = valid ? sa[mt][nt][r] : -1e9f;
            }
        }

        // ---- online softmax (C layout: col=lane&15, row=quad*4+r)
#pragma unroll
        for (int mt = 0; mt < 2; mt++) {
            float al[4];
#pragma unroll
            for (int r = 0; r < 4; r++) {
                float mx = fmaxf(fmaxf(sa[mt][0][r], sa[mt][1][r]),
                                 fmaxf(sa[mt][2][r], sa[mt][3][r]));
#pragma unroll
                for (int off = 1; off < 16; off <<= 1)
                    mx = fmaxf(mx, __shfl_xor(mx, off, 16));
                const float mn = fmaxf(mrow[mt][r], mx);
                al[r] = __expf(mrow[mt][r] - mn);
                mrow[mt][r] = mn;
                float ps = 0.f;
#pragma unroll
                for (int nt = 0; nt < 4; nt++) {
                    const float p = __expf(sa[mt][nt][r] - mn);
                    sa[mt][nt][r] = p;
                    ps += p;
                }
#pragma unroll
                for (int off = 1; off < 16; off <<= 1) ps += __shfl_xor(ps, off, 16);
                lrow[mt][r] = lrow[mt][r] * al[r] + ps;
            }
            // P -> LDS (bf16), wave-private rows
#pragma unroll
            for (int nt = 0; nt < 4; nt++)
#pragma unroll
                for (int r = 0; r < 4; r++)
                    Ps[(w * 32 + mt * 16 + quad * 4 + r) * 72 + nt * 16 + l] =
                        f2bf(sa[mt][nt][r]);
            // rescale O
#pragma unroll
            for (int nt = 0; nt < 8; nt++)
#pragma unroll
                for (int r = 0; r < 4; r++) o_acc[mt][nt][r] *= al[r];
        }

        // ---- O += P V   (A = P from own LDS rows, B = Vt)
#pragma unroll
        for (int ks = 0; ks < 2; ks++) {
            short8 pf[2];
#pragma unroll
            for (int mt = 0; mt < 2; mt++)
                pf[mt] = *(const short8*)&Ps[(w * 32 + mt * 16 + l) * 72 + ks * 32 + quad * 8];
#pragma unroll
            for (int nt = 0; nt < 8; nt++) {
                const short8 vf =
                    *(const short8*)&Vts[(nt * 16 + l) * 72 + ks * 32 + quad * 8];
#pragma unroll
                for (int mt = 0; mt < 2; mt++)
                    o_acc[mt][nt] = __builtin_amdgcn_mfma_f32_16x16x32_bf16(
                        pf[mt], vf, o_acc[mt][nt], 0, 0, 0);
            }
        }
    }

    // ---- epilogue: normalize, write bf16 O as [B][S][H*DH]
#pragma unroll
    for (int mt = 0; mt < 2; mt++)
#pragma unroll
        for (int r = 0; r < 4; r++) {
            const float inv = 1.0f / lrow[mt][r];
            const int s = q0 + w * 32 + mt * 16 + quad * 4 + r;
            ushort* dst = ob + ((size_t)b * S_TOT + s) * D_MODEL + h * DHEAD;
#pragma unroll
            for (int nt = 0; nt < 8; nt++)
                dst[nt * 16 + l] = f2bf(o_acc[mt][nt][r] * inv);
        }
}

// ---------------------------------------------------------------------------
extern "C" void kernel_launch(void* const* d_in, const int* in_sizes, int n_in,
                              void* d_out, int out_size, void* d_ws, size_t ws_size,
                              hipStream_t stream)
{
    const float* hidden = (const float*)d_in[0];
    const float* enc    = (const float*)d_in[1];
    const int* encmask  = (const int*)d_in[2];
    const float* icos = (const float*)d_in[4];
    const float* isin = (const float*)d_in[5];
    const float* tcos = (const float*)d_in[6];
    const float* tsin = (const float*)d_in[7];
    const float* wq  = (const float*)d_in[8];  const float* bq  = (const float*)d_in[9];
    const float* wk  = (const float*)d_in[10]; const float* bk  = (const float*)d_in[11];
    const float* wv  = (const float*)d_in[12]; const float* bv  = (const float*)d_in[13];
    const float* wqa = (const float*)d_in[14]; const float* bqa = (const float*)d_in[15];
    const float* wka = (const float*)d_in[16]; const float* bka = (const float*)d_in[17];
    const float* wva = (const float*)d_in[18]; const float* bva = (const float*)d_in[19];
    const float* wo  = (const float*)d_in[20]; const float* bo  = (const float*)d_in[21];
    const float* woa = (const float*)d_in[22]; const float* boa = (const float*)d_in[23];
    const float* gq  = (const float*)d_in[24]; const float* gk  = (const float*)d_in[25];
    const float* gqa = (const float*)d_in[26]; const float* gka = (const float*)d_in[27];
    float* out = (float*)d_out;

    const size_t W_ELE = (size_t)D_MODEL * D_MODEL;
    const size_t NQKV  = (size_t)BATCH * NHEADS * S_TOT * DHEAD;
    char* p = (char*)d_ws;
    ushort* wT0 = (ushort*)p; p += W_ELE * 2;
    ushort* wT1 = (ushort*)p; p += W_ELE * 2;
    ushort* wT2 = (ushort*)p; p += W_ELE * 2;
    ushort* ximg = (ushort*)p; p += (size_t)BATCH * S_IMGC * D_MODEL * 2;
    ushort* xtxt = (ushort*)p; p += (size_t)BATCH * S_TXTC * D_MODEL * 2;
    ushort* qbuf = (ushort*)p; p += NQKV * 2;
    ushort* kbuf = (ushort*)p; p += NQKV * 2;
    ushort* vbuf = (ushort*)p; p += NQKV * 2;
    ushort* vtbuf = (ushort*)p; p += NQKV * 2;
    ushort* obuf = (ushort*)p; p += (size_t)BATCH * S_TOT * D_MODEL * 2;
    if ((size_t)(p - (char*)d_ws) > ws_size) return;  // 226.5 MB needed

    const dim3 blk(256);

    cvt_kernel<<<dim3((BATCH * S_IMGC * D_MODEL / 4 + 255) / 256), blk, 0, stream>>>(
        hidden, ximg, BATCH * S_IMGC * D_MODEL / 4);
    cvt_kernel<<<dim3((BATCH * S_TXTC * D_MODEL / 4 + 255) / 256), blk, 0, stream>>>(
        enc, xtxt, BATCH * S_TXTC * D_MODEL / 4);

    transpose_w<<<dim3(48, 48, 3), blk, 0, stream>>>(wq, wk, wv, wT0, wT1, wT2);
    gemm_bf16<true><<<dim3(32, 24, 3), blk, 0, stream>>>(
        ximg, (size_t)S_IMGC * D_MODEL, 0, S_IMGC,
        wT0, wT1, wT2, bq, bk, bv, qbuf, kbuf, vbuf, nullptr, 0);
    transpose_w<<<dim3(48, 48, 3), blk, 0, stream>>>(wqa, wka, wva, wT0, wT1, wT2);
    gemm_bf16<true><<<dim3(4, 24, 3), blk, 0, stream>>>(
        xtxt, (size_t)S_TXTC * D_MODEL, 0, S_TXTC,
        wT0, wT1, wT2, bqa, bka, bva, qbuf, kbuf, vbuf, nullptr, S_IMGC);

    rmsrope_kernel<<<dim3(BATCH * NHEADS * S_TOT / 4, 2), blk, 0, stream>>>(
        qbuf, kbuf, gq, gk, gqa, gka, icos, isin, tcos, tsin);

    transpose_v<<<dim3(S_TOT / 64, DHEAD / 64, BATCH * NHEADS), blk, 0, stream>>>(
        vbuf, vtbuf);

    attn_kernel<<<dim3(S_TOT / 128, NHEADS, BATCH), blk, 0, stream>>>(
        qbuf, kbuf, vtbuf, obuf, encmask);

    transpose_w<<<dim3(48, 48, 1), blk, 0, stream>>>(wo, wo, wo, wT0, wT0, wT0);
    gemm_bf16<false><<<dim3(32, 24, 1), blk, 0, stream>>>(
        obuf, (size_t)S_TOT * D_MODEL, 0, S_IMGC,
        wT0, wT0, wT0, bo, bo, bo, nullptr, nullptr, nullptr, out, 0);
    transpose_w<<<dim3(48, 48, 1), blk, 0, stream>>>(woa, woa, woa, wT0, wT0, wT0);
    gemm_bf16<false><<<dim3(4, 24, 1), blk, 0, stream>>>(
        obuf, (size_t)S_TOT * D_MODEL, S_IMGC, S_TXTC,
        wT0, wT0, wT0, boa, boa, boa, nullptr, nullptr, nullptr,
        out + (size_t)BATCH * S_IMGC * D_MODEL, 0);
}